// Round 1
// baseline (519.500 us; speedup 1.0000x reference)
//
#include <hip/hip_runtime.h>

#define N_IN   128
#define VV     2
#define DD     256
#define KSEL   4096
#define NBATCH 8
#define NREP   8

// monotone map: float ordering -> unsigned ordering
__device__ __forceinline__ unsigned keyOf(float s){
    unsigned b = __float_as_uint(s);
    return (b & 0x80000000u) ? ~b : (b | 0x80000000u);
}

// ---------------------------------------------------------------------------
// Kernel 1: scores. One wave handles 2 rows per iteration (64 lanes x float4
// = 256 floats = 2 rows). fp64 accumulate -> fp32 score -> radix key.
// ---------------------------------------------------------------------------
__global__ __launch_bounds__(256) void scores_kernel(
        const float* __restrict__ x, const float* __restrict__ W_fr,
        const float* __restrict__ b_fr, unsigned* __restrict__ keys,
        int N, int totalWaves)
{
    const int tid  = blockIdx.x * blockDim.x + threadIdx.x;
    const int wave = tid >> 6;
    const int lane = tid & 63;
    const int f = 4 * (lane & 31);
    const float w00 = W_fr[(f+0)*2+0], w01 = W_fr[(f+0)*2+1];
    const float w10 = W_fr[(f+1)*2+0], w11 = W_fr[(f+1)*2+1];
    const float w20 = W_fr[(f+2)*2+0], w21 = W_fr[(f+2)*2+1];
    const float w30 = W_fr[(f+3)*2+0], w31 = W_fr[(f+3)*2+1];
    const float bf0 = b_fr[0], bf1 = b_fr[1];
    const int half = N >> 1;
    for (int rp = wave; rp < half; rp += totalWaves){
        const int r0 = rp * 2;
        const float4 xv = *reinterpret_cast<const float4*>(x + (size_t)r0 * N_IN + 4*lane);
        double p0 = (double)xv.x*w00 + (double)xv.y*w10 + (double)xv.z*w20 + (double)xv.w*w30;
        double p1 = (double)xv.x*w01 + (double)xv.y*w11 + (double)xv.z*w21 + (double)xv.w*w31;
        #pragma unroll
        for (int off = 16; off; off >>= 1){
            p0 += __shfl_xor(p0, off, 32);
            p1 += __shfl_xor(p1, off, 32);
        }
        const int r = r0 + (lane >> 5);            // lanes 0-31 -> r0, 32-63 -> r0+1
        if ((lane & 31) == 0) keys[r]     = keyOf((float)(p0 + bf0));
        if ((lane & 31) == 1) keys[N + r] = keyOf((float)(p1 + bf1));
    }
}

// ---------------------------------------------------------------------------
// Kernel 2: exact top-K radix select per (batch,virtual) group.
// 16 blocks x 1024 threads. 3-level histogram (11/11/10 bits) finds the exact
// K-th key; phase D does a stable ordered scan: all keys > utar selected,
// plus the lowest-index (K - #greater) keys equal to utar (top_k tiebreak).
// Writes byte mask + index-sorted selection list.
// ---------------------------------------------------------------------------
__global__ __launch_bounds__(1024) void select_kernel(
        const unsigned* __restrict__ keys,
        unsigned char* __restrict__ mask,
        int* __restrict__ lists,
        int N, int R)
{
    const int g = blockIdx.x, b = g >> 1, v = g & 1;
    const unsigned* kk = keys + (size_t)v * N + (size_t)b * R;
    const int tid  = threadIdx.x;
    const int wave = tid >> 6, lane = tid & 63;

    __shared__ unsigned hist[NREP][2048];
    __shared__ unsigned coarse[32];
    __shared__ unsigned sOut[2];
    __shared__ unsigned waveA[16], waveB[16];
    __shared__ unsigned sBaseEq, sBaseSel;

    // ---------------- phase A: top 11 bits ----------------
    for (int i = tid; i < NREP*2048; i += 1024) (&hist[0][0])[i] = 0u;
    __syncthreads();
    for (int i = tid; i < R; i += 1024){
        unsigned u = kk[i];
        atomicAdd(&hist[wave & (NREP-1)][u >> 21], 1u);
    }
    __syncthreads();
    for (int bin = tid; bin < 2048; bin += 1024){
        unsigned s = 0;
        #pragma unroll
        for (int rp = 0; rp < NREP; ++rp) s += hist[rp][bin];
        hist[0][bin] = s;
    }
    __syncthreads();
    if (tid < 32){ unsigned s = 0; for (int j = 0; j < 64; ++j) s += hist[0][tid*64+j]; coarse[tid] = s; }
    __syncthreads();
    if (tid == 0){
        unsigned kneed = KSEL, cum = 0; int cb = 31;
        for (; cb > 0; --cb){ if (cum + coarse[cb] >= kneed) break; cum += coarse[cb]; }
        int bin = cb*64 + 63;
        for (; bin > cb*64; --bin){ if (cum + hist[0][bin] >= kneed) break; cum += hist[0][bin]; }
        sOut[0] = (unsigned)bin; sOut[1] = kneed - cum;
    }
    __syncthreads();
    const unsigned B1 = sOut[0];
    const unsigned kneed1 = sOut[1];
    __syncthreads();

    // ---------------- phase B: mid 11 bits ----------------
    for (int i = tid; i < NREP*2048; i += 1024) (&hist[0][0])[i] = 0u;
    __syncthreads();
    for (int i = tid; i < R; i += 1024){
        unsigned u = kk[i];
        if ((u >> 21) == B1) atomicAdd(&hist[wave & (NREP-1)][(u >> 10) & 0x7FFu], 1u);
    }
    __syncthreads();
    for (int bin = tid; bin < 2048; bin += 1024){
        unsigned s = 0;
        #pragma unroll
        for (int rp = 0; rp < NREP; ++rp) s += hist[rp][bin];
        hist[0][bin] = s;
    }
    __syncthreads();
    if (tid < 32){ unsigned s = 0; for (int j = 0; j < 64; ++j) s += hist[0][tid*64+j]; coarse[tid] = s; }
    __syncthreads();
    if (tid == 0){
        unsigned kneed = kneed1, cum = 0; int cb = 31;
        for (; cb > 0; --cb){ if (cum + coarse[cb] >= kneed) break; cum += coarse[cb]; }
        int bin = cb*64 + 63;
        for (; bin > cb*64; --bin){ if (cum + hist[0][bin] >= kneed) break; cum += hist[0][bin]; }
        sOut[0] = (unsigned)bin; sOut[1] = kneed - cum;
    }
    __syncthreads();
    const unsigned B2 = sOut[0];
    const unsigned kneed2 = sOut[1];
    const unsigned top22 = (B1 << 11) | B2;
    __syncthreads();

    // ---------------- phase C: low 10 bits ----------------
    for (int i = tid; i < NREP*2048; i += 1024) (&hist[0][0])[i] = 0u;
    __syncthreads();
    for (int i = tid; i < R; i += 1024){
        unsigned u = kk[i];
        if ((u >> 10) == top22) atomicAdd(&hist[wave & (NREP-1)][u & 0x3FFu], 1u);
    }
    __syncthreads();
    for (int bin = tid; bin < 1024; bin += 1024){
        unsigned s = 0;
        #pragma unroll
        for (int rp = 0; rp < NREP; ++rp) s += hist[rp][bin];
        hist[0][bin] = s;
    }
    __syncthreads();
    if (tid < 32){ unsigned s = 0; for (int j = 0; j < 32; ++j) s += hist[0][tid*32+j]; coarse[tid] = s; }
    __syncthreads();
    if (tid == 0){
        unsigned kneed = kneed2, cum = 0; int cb = 31;
        for (; cb > 0; --cb){ if (cum + coarse[cb] >= kneed) break; cum += coarse[cb]; }
        int bin = cb*32 + 31;
        for (; bin > cb*32; --bin){ if (cum + hist[0][bin] >= kneed) break; cum += hist[0][bin]; }
        sOut[0] = (unsigned)bin; sOut[1] = kneed - cum;
    }
    __syncthreads();
    const unsigned B3 = sOut[0];
    const unsigned take_eq = sOut[1];
    const unsigned utar = (B1 << 21) | (B2 << 10) | B3;

    // ---------------- phase D: stable mask + ordered compact list ----------------
    if (tid == 0){ sBaseEq = 0; sBaseSel = 0; }
    __syncthreads();
    unsigned char* mk = mask + (size_t)v * N + (size_t)b * R;
    int* lst = lists + g * KSEL;
    for (int start = 0; start < R; start += 1024){
        const int i = start + tid;
        const unsigned u = (i < R) ? kk[i] : 0u;
        const bool gt = (i < R) && (u > utar);
        const bool eq = (i < R) && (u == utar);
        unsigned long long mEq = __ballot(eq);
        if (lane == 0) waveA[wave] = (unsigned)__popcll(mEq);
        __syncthreads();
        unsigned eqPref = sBaseEq;
        for (int w = 0; w < wave; ++w) eqPref += waveA[w];
        unsigned eqTot = 0;
        for (int w = 0; w < 16; ++w) eqTot += waveA[w];
        const unsigned eqRank = eqPref + (unsigned)__popcll(mEq & ((1ULL << lane) - 1ULL));
        const bool sel = gt || (eq && eqRank < take_eq);
        unsigned long long mSel = __ballot(sel);
        if (lane == 0) waveB[wave] = (unsigned)__popcll(mSel);
        __syncthreads();
        unsigned selPref = sBaseSel;
        for (int w = 0; w < wave; ++w) selPref += waveB[w];
        unsigned selTot = 0;
        for (int w = 0; w < 16; ++w) selTot += waveB[w];
        if (i < R){
            mk[i] = sel ? (unsigned char)1 : (unsigned char)0;
            if (sel) lst[selPref + (unsigned)__popcll(mSel & ((1ULL << lane) - 1ULL))] = i;
        }
        __syncthreads();
        if (tid == 0){ sBaseEq += eqTot; sBaseSel += selTot; }
        __syncthreads();
    }
}

// ---------------------------------------------------------------------------
// Kernel 3: gather selected rows and produce deterministic fp64 partial sums.
// grid = 16 groups x 64 chunks; each block sums 64 selected rows.
// ---------------------------------------------------------------------------
__global__ __launch_bounds__(256) void virt_partial_kernel(
        const float* __restrict__ x, const int* __restrict__ lists,
        double* __restrict__ part, int R)
{
    const int g = blockIdx.x >> 6;
    const int m = blockIdx.x & 63;
    const int b = g >> 1;
    const int tid = threadIdx.x, wave = tid >> 6, lane = tid & 63;
    const int* lst = lists + g * KSEL + m * 64;
    int idxs[16];
    #pragma unroll
    for (int e = 0; e < 16; ++e) idxs[e] = lst[e*4 + wave];
    double a0 = 0.0, a1 = 0.0;
    #pragma unroll
    for (int e = 0; e < 16; ++e){
        const float2 xv = *reinterpret_cast<const float2*>(
            x + ((size_t)b * R + idxs[e]) * N_IN + 2*lane);
        a0 += xv.x; a1 += xv.y;
    }
    __shared__ double pp[4][128];
    pp[wave][2*lane]   = a0;
    pp[wave][2*lane+1] = a1;
    __syncthreads();
    if (tid < 128){
        double s = pp[0][tid] + pp[1][tid] + pp[2][tid] + pp[3][tid];
        part[(size_t)(g*64 + m) * N_IN + tid] = s;
    }
}

// ---------------------------------------------------------------------------
// Kernel 4: reduce partials -> virt (/K), then the tiny 2-layer MLP.
// 8 blocks (one per batch) x 256 threads.
// ---------------------------------------------------------------------------
__global__ __launch_bounds__(256) void mlp_kernel(
        const double* __restrict__ part,
        const float* __restrict__ W1, const float* __restrict__ b1,
        const float* __restrict__ W2, const float* __restrict__ b2,
        float* __restrict__ upd)
{
    const int b = blockIdx.x, j = threadIdx.x;
    __shared__ float inv[DD];
    __shared__ float h1[DD];
    {
        const int g = b*2 + (j >> 7);
        const int f = j & 127;
        const double* p = part + (size_t)g * 64 * N_IN + f;
        double s = 0.0;
        for (int m = 0; m < 64; ++m) s += p[(size_t)m * N_IN];
        inv[j] = (float)(s / (double)KSEL);
    }
    __syncthreads();
    double acc = 0.0;
    for (int i = 0; i < DD; ++i) acc += (double)inv[i] * (double)W1[i*DD + j];
    h1[j] = fmaxf((float)(acc + (double)b1[j]), 0.0f);
    __syncthreads();
    acc = 0.0;
    for (int i = 0; i < DD; ++i) acc += (double)h1[i] * (double)W2[i*DD + j];
    upd[b*DD + j] = (float)(acc + (double)b2[j]);
}

// ---------------------------------------------------------------------------
// Kernel 5: final blend. out = x; if sel0: out=(out+u0)*0.5; if sel1: ...
// One float4 per thread-iteration; 32 consecutive threads = one row.
// ---------------------------------------------------------------------------
__global__ __launch_bounds__(256) void final_kernel(
        const float* __restrict__ x,
        const unsigned char* __restrict__ mask,
        const float* __restrict__ upd,
        float* __restrict__ out, int N, int R)
{
    const int nvec = N * (N_IN / 4);
    const int stride = gridDim.x * blockDim.x;
    for (int idx = blockIdx.x * blockDim.x + threadIdx.x; idx < nvec; idx += stride){
        const int row = idx >> 5;
        const int c = (idx & 31) * 4;
        float4 o = *reinterpret_cast<const float4*>(x + (size_t)row * N_IN + c);
        const int b = row / R;
        const unsigned char m0 = mask[row];
        const unsigned char m1 = mask[(size_t)N + row];
        if (m0){
            const float4 u0 = *reinterpret_cast<const float4*>(upd + b*DD + c);
            o.x = (o.x + u0.x)*0.5f; o.y = (o.y + u0.y)*0.5f;
            o.z = (o.z + u0.z)*0.5f; o.w = (o.w + u0.w)*0.5f;
        }
        if (m1){
            const float4 u1 = *reinterpret_cast<const float4*>(upd + b*DD + 128 + c);
            o.x = (o.x + u1.x)*0.5f; o.y = (o.y + u1.y)*0.5f;
            o.z = (o.z + u1.z)*0.5f; o.w = (o.w + u1.w)*0.5f;
        }
        *reinterpret_cast<float4*>(out + (size_t)row * N_IN + c) = o;
    }
}

extern "C" void kernel_launch(void* const* d_in, const int* in_sizes, int n_in_cnt,
                              void* d_out, int out_size, void* d_ws, size_t ws_size,
                              hipStream_t stream)
{
    const float* x    = (const float*)d_in[0];
    const float* W_fr = (const float*)d_in[1];
    const float* b_fr = (const float*)d_in[2];
    const float* W1   = (const float*)d_in[3];
    const float* b1   = (const float*)d_in[4];
    const float* W2   = (const float*)d_in[5];
    const float* b2   = (const float*)d_in[6];
    float* out = (float*)d_out;

    const int N = in_sizes[0] / N_IN;   // 800000
    const int R = N / NBATCH;           // 100000

    char* ws = (char*)d_ws;
    size_t off = 0;
    auto alloc = [&](size_t bytes) -> void* {
        void* p = ws + off;
        off = (off + bytes + 255) & ~(size_t)255;
        return p;
    };
    unsigned char* mask = (unsigned char*)alloc((size_t)2 * N);
    int*    lists = (int*)   alloc((size_t)16 * KSEL * 4);
    double* part  = (double*)alloc((size_t)16 * 64 * N_IN * 8);
    float*  upd   = (float*) alloc((size_t)NBATCH * DD * 4);

    unsigned* keys;
    const size_t keyBytes = (size_t)2 * N * 4;
    if (off + keyBytes <= ws_size){
        keys = (unsigned*)alloc(keyBytes);
    } else {
        // fall back: stash keys in the tail of d_out (final_kernel overwrites
        // it only after all consumers of keys have run; stream-ordered).
        keys = (unsigned*)((char*)d_out + (size_t)out_size * 4 - keyBytes);
    }

    const int totalWaves = 2048 * 256 / 64;
    scores_kernel<<<dim3(2048), dim3(256), 0, stream>>>(x, W_fr, b_fr, keys, N, totalWaves);
    select_kernel<<<dim3(16), dim3(1024), 0, stream>>>(keys, mask, lists, N, R);
    virt_partial_kernel<<<dim3(16*64), dim3(256), 0, stream>>>(x, lists, part, R);
    mlp_kernel<<<dim3(NBATCH), dim3(DD), 0, stream>>>(part, W1, b1, W2, b2, upd);
    final_kernel<<<dim3(2048), dim3(256), 0, stream>>>(x, mask, upd, out, N, R);
}